// Round 7
// baseline (26.268 us; speedup 1.0000x reference)
//
#include <hip/hip_runtime.h>
#include <math.h>

// Numerics FROZEN from round 6 (passing): jax XLA:CPU f32 model —
//   f32 linspace t=RN(i*RN(1/31)); correctly-rounded powers (f64-emulated);
//   samples dot = sequential mul-then-add (no fma); cross = K=2 FMA chain;
//   s2 = RN(RN(sy^2)+RN(sx^2)); d2 = RN(RN(p2-2c)+s2).
// Round 7 is a pure PERFORMANCE restructure: samples move from LDS broadcasts
// (96 ds_read/wave — the bottleneck pipe) to SGPR operands via a tiny
// precompute kernel + wave-uniform loads (readfirstlane-forced).
#define OPAQ(x) asm volatile("" : "+v"(x))

#define HH 256
#define WW 256
#define NS 32
#define NB 32

__device__ __forceinline__ float rfl(float v) {
    int i = __builtin_amdgcn_readfirstlane(__builtin_bit_cast(int, v));
    return __builtin_bit_cast(float, i);
}

// ---- shared numeric core: compute sample s of batch b (EXACT round-6 ops) ----
__device__ __forceinline__ void curve_sample(const float* kp, int s,
                                             float& accy_o, float& accx_o, float& s2_o) {
    const float STEP = 1.0f / 31.0f;       // RN(1/31)
    float t = (float)s * STEP; OPAQ(t);    // f32 linspace (i=31 -> rounds to 1.0)
    float u = 1.0f - t;        OPAQ(u);
    // correctly-rounded powers (glibc powf) emulated via exact f64 products
    float t2 = (float)((double)t * (double)t);
    float t3 = (float)((double)t * (double)t * (double)t);
    float u2 = (float)((double)u * (double)u);
    float u3 = (float)((double)u * (double)u * (double)u);
    float b0 = u3;
    float m1 = 3.0f * t;  OPAQ(m1); float b1 = m1 * u2; OPAQ(b1);
    float m2 = 3.0f * t2; OPAQ(m2); float b2 = m2 * u;  OPAQ(b2);
    float b3 = t3;

    float ky0 = kp[0] * 256.0f, kx0 = kp[1] * 256.0f;   // exact (x 2^8)
    float ky1 = kp[2] * 256.0f, kx1 = kp[3] * 256.0f;
    float ky2 = kp[4] * 256.0f, kx2 = kp[5] * 256.0f;
    float ky3 = kp[6] * 256.0f, kx3 = kp[7] * 256.0f;

    // samples dot: sequential mul THEN add, no fma (XLA naive small-dot)
    float p, accy, accx;
    p = b0 * ky0; OPAQ(p); accy = p;
    p = b1 * ky1; OPAQ(p); accy = accy + p; OPAQ(accy);
    p = b2 * ky2; OPAQ(p); accy = accy + p; OPAQ(accy);
    p = b3 * ky3; OPAQ(p); accy = accy + p; OPAQ(accy);

    p = b0 * kx0; OPAQ(p); accx = p;
    p = b1 * kx1; OPAQ(p); accx = accx + p; OPAQ(accx);
    p = b2 * kx2; OPAQ(p); accx = accx + p; OPAQ(accx);
    p = b3 * kx3; OPAQ(p); accx = accx + p; OPAQ(accx);

    float q1 = accy * accy; OPAQ(q1);
    float q2 = accx * accx; OPAQ(q2);
    accy_o = accy; accx_o = accx; s2_o = q1 + q2;
}

// ---- kernel 1: 32 batches -> ws[b*96 + {0:sy,32:sx,64:s2}] ----
__global__ __launch_bounds__(64) void curve_samples_kernel(
    const float* __restrict__ in, float* __restrict__ ws)
{
    const int b = blockIdx.x;
    const int s = threadIdx.x;
    if (s < NS) {
        float sy, sx, s2v;
        curve_sample(in + b * 8, s, sy, sx, s2v);
        float* w = ws + b * 96;
        w[s] = sy; w[NS + s] = sx; w[2 * NS + s] = s2v;
    }
}

// ---- kernel 2: render, samples as SGPR operands (no LDS in hot loop) ----
__global__ __launch_bounds__(256) void curve_render_kernel(
    const float* __restrict__ ws, float* __restrict__ out)
{
    const int b   = blockIdx.x >> 8;
    const int row = blockIdx.x & 255;
    const int tid = threadIdx.x;
    const float* __restrict__ sp = ws + b * 96;   // wave-uniform base

    const float y  = (float)row;
    const float x  = (float)tid;
    const float p2 = y * y + x * x;               // exact (integers < 2^24)

    float mind2 = 3.4028234663852886e38f;
    #pragma unroll
    for (int s = 0; s < NS; ++s) {
        const float sy_s = rfl(sp[s]);            // SGPR
        const float sx_s = rfl(sp[NS + s]);       // SGPR
        const float s2_s = rfl(sp[2 * NS + s]);   // SGPR
        // cross (Eigen gemm K=2): c = fma(x, sx, RN(y*sy))
        float c0 = y * sy_s;         OPAQ(c0);    // v_mul v,s,v
        float c  = fmaf(x, sx_s, c0); OPAQ(c);    // v_fma v,s,v,v
        // d2 = RN( RN(p2 - 2c) + s2 ); 2c exact so fma(-2,c,p2) == RN(p2-2c)
        float e  = p2 - 2.0f * c;                 // v_fma (exact either way)
        float d2 = e + s2_s;                      // v_add v,s,v
        mind2 = fminf(mind2, d2);
    }
    mind2 = fmaxf(mind2, 0.0f);
    float md = sqrtf(mind2);              // IEEE RN
    float r  = md * 0.25f + 1e-6f;        // exact /4 ; RN(+1e-6f)
    float w  = powf(r, 0.35f);            // final op
    out[(b * HH + row) * WW + tid] = 1.0f - w;
}

// ---- fallback (round-6 single kernel, LDS path) if ws too small ----
__global__ __launch_bounds__(256) void curve_fused_kernel(
    const float* __restrict__ in, float* __restrict__ out)
{
    __shared__ float sy[NS], sx[NS], s2[NS];
    const int b   = blockIdx.x >> 8;
    const int row = blockIdx.x & 255;
    const int tid = threadIdx.x;

    if (tid < NS) {
        float a, c, d;
        curve_sample(in + b * 8, tid, a, c, d);
        sy[tid] = a; sx[tid] = c; s2[tid] = d;
    }
    __syncthreads();

    const float y = (float)row, x = (float)tid;
    const float p2 = y * y + x * x;
    float mind2 = 3.4028234663852886e38f;
    #pragma unroll
    for (int s = 0; s < NS; ++s) {
        float c0 = y * sy[s]; OPAQ(c0);
        float c  = fmaf(x, sx[s], c0); OPAQ(c);
        float e  = p2 - 2.0f * c;
        float d2 = e + s2[s];
        mind2 = fminf(mind2, d2);
    }
    mind2 = fmaxf(mind2, 0.0f);
    float md = sqrtf(mind2);
    float r  = md * 0.25f + 1e-6f;
    float w  = powf(r, 0.35f);
    out[(b * HH + row) * WW + tid] = 1.0f - w;
}

extern "C" void kernel_launch(void* const* d_in, const int* in_sizes, int n_in,
                              void* d_out, int out_size, void* d_ws, size_t ws_size,
                              hipStream_t stream) {
    const float* in = (const float*)d_in[0];
    float* out = (float*)d_out;
    if (ws_size >= (size_t)(NB * 96 * sizeof(float)) && d_ws != nullptr) {
        float* ws = (float*)d_ws;
        curve_samples_kernel<<<dim3(NB), dim3(64), 0, stream>>>(in, ws);
        curve_render_kernel<<<dim3(NB * HH), dim3(256), 0, stream>>>(ws, out);
    } else {
        curve_fused_kernel<<<dim3(NB * HH), dim3(256), 0, stream>>>(in, out);
    }
}

// Round 9
// 16.235 us; speedup vs baseline: 1.6180x; 1.6180x over previous
//
#include <hip/hip_runtime.h>
#include <math.h>

// Numerics FROZEN (passed rounds 6 & 7): jax XLA:CPU f32 model —
//   f32 linspace t=RN(i*RN(1/31)); correctly-rounded powers (f64-emulated);
//   samples dot = sequential mul-then-add (no fma); cross = K=2 FMA chain;
//   s2 = RN(RN(sy^2)+RN(sx^2)); d2 = RN(RN(p2-2c)+s2); min; clamp.
// Round 9 = round 8 structure with compile fix: HW transcendentals via
// inline asm (v_sqrt_f32 / v_log_f32 / v_exp_f32 — ISA §3), since
// __exp2f/__log2f are CUDA-only and broke the build.
//   - every lane computes sample (lane&31); loop reads via v_readlane -> SGPR
//   - 4 px/thread, c0 = y*sy shared per wave (bitwise-identical), float4 store
//   - tail error <= ~1e-6 + one bf16 quantum worst case (margin 0.0175)
#define OPAQ(x) asm volatile("" : "+v"(x))

#define HH 256
#define WW 256
#define NS 32
#define NB 32

__device__ __forceinline__ float rlane(float v, int lane) {
    int i = __builtin_amdgcn_readlane(__builtin_bit_cast(int, v), lane);
    return __builtin_bit_cast(float, i);
}
__device__ __forceinline__ float hw_sqrt(float x) {
    float r; asm("v_sqrt_f32 %0, %1" : "=v"(r) : "v"(x)); return r;
}
__device__ __forceinline__ float hw_log2(float x) {
    float r; asm("v_log_f32 %0, %1" : "=v"(r) : "v"(x)); return r;
}
__device__ __forceinline__ float hw_exp2(float x) {
    float r; asm("v_exp_f32 %0, %1" : "=v"(r) : "v"(x)); return r;
}

// ---- frozen numeric core: sample s of one curve (EXACT round-6 ops) ----
__device__ __forceinline__ void curve_sample(const float* kp, int s,
                                             float& accy_o, float& accx_o, float& s2_o) {
    const float STEP = 1.0f / 31.0f;       // RN(1/31)
    float t = (float)s * STEP; OPAQ(t);    // f32 linspace (i=31 -> 1.0 after RN)
    float u = 1.0f - t;        OPAQ(u);
    // correctly-rounded powers (glibc powf) emulated via exact f64 products
    float t2 = (float)((double)t * (double)t);
    float t3 = (float)((double)t * (double)t * (double)t);
    float u2 = (float)((double)u * (double)u);
    float u3 = (float)((double)u * (double)u * (double)u);
    float b0 = u3;
    float m1 = 3.0f * t;  OPAQ(m1); float b1 = m1 * u2; OPAQ(b1);
    float m2 = 3.0f * t2; OPAQ(m2); float b2 = m2 * u;  OPAQ(b2);
    float b3 = t3;

    float ky0 = kp[0] * 256.0f, kx0 = kp[1] * 256.0f;   // exact (x 2^8)
    float ky1 = kp[2] * 256.0f, kx1 = kp[3] * 256.0f;
    float ky2 = kp[4] * 256.0f, kx2 = kp[5] * 256.0f;
    float ky3 = kp[6] * 256.0f, kx3 = kp[7] * 256.0f;

    // samples dot: sequential mul THEN add, no fma (XLA naive small-dot)
    float p, accy, accx;
    p = b0 * ky0; OPAQ(p); accy = p;
    p = b1 * ky1; OPAQ(p); accy = accy + p; OPAQ(accy);
    p = b2 * ky2; OPAQ(p); accy = accy + p; OPAQ(accy);
    p = b3 * ky3; OPAQ(p); accy = accy + p; OPAQ(accy);

    p = b0 * kx0; OPAQ(p); accx = p;
    p = b1 * kx1; OPAQ(p); accx = accx + p; OPAQ(accx);
    p = b2 * kx2; OPAQ(p); accx = accx + p; OPAQ(accx);
    p = b3 * kx3; OPAQ(p); accx = accx + p; OPAQ(accx);

    float q1 = accy * accy; OPAQ(q1);
    float q2 = accx * accx; OPAQ(q2);
    accy_o = accy; accx_o = accx; s2_o = q1 + q2;
}

__global__ __launch_bounds__(256) void curve_render_kernel(
    const float* __restrict__ in, float* __restrict__ out)
{
    const int b    = blockIdx.x >> 6;      // image
    const int rg   = blockIdx.x & 63;      // row-group (4 rows per block)
    const int wid  = threadIdx.x >> 6;     // wave id = row within group
    const int lane = threadIdx.x & 63;
    const int row  = (rg << 2) + wid;

    // every lane computes sample (lane & 31); lanes 32-63 duplicate 0-31
    float v_sy, v_sx, v_s2;
    curve_sample(in + b * 8, lane & 31, v_sy, v_sx, v_s2);

    const float y  = (float)row;
    const float x0 = (float)(lane << 2);
    const float x1 = x0 + 1.0f, x2 = x0 + 2.0f, x3 = x0 + 3.0f;
    const float p20 = y * y + x0 * x0;     // exact (integers < 2^24)
    const float p21 = y * y + x1 * x1;
    const float p22 = y * y + x2 * x2;
    const float p23 = y * y + x3 * x3;

    const float INF = 3.4028234663852886e38f;
    float m0 = INF, m1 = INF, m2 = INF, m3 = INF;

    #pragma unroll
    for (int s = 0; s < NS; ++s) {
        const float sy_s = rlane(v_sy, s);   // SGPR
        const float sx_s = rlane(v_sx, s);   // SGPR
        const float s2_s = rlane(v_s2, s);   // SGPR
        // c0 = RN(y*sy): shared across the 4 pixels (bitwise-identical op)
        float c0 = y * sy_s; OPAQ(c0);       // v_mul v,s,v
        // per pixel: c = fma(x, sx, c0); e = RN(p2 - 2c) (2c exact, fma-safe);
        //            d2 = RN(e + s2); min
        float c, e, d2;
        c = fmaf(x0, sx_s, c0); e = p20 - 2.0f * c; d2 = e + s2_s; m0 = fminf(m0, d2);
        c = fmaf(x1, sx_s, c0); e = p21 - 2.0f * c; d2 = e + s2_s; m1 = fminf(m1, d2);
        c = fmaf(x2, sx_s, c0); e = p22 - 2.0f * c; d2 = e + s2_s; m2 = fminf(m2, d2);
        c = fmaf(x3, sx_s, c0); e = p23 - 2.0f * c; d2 = e + s2_s; m3 = fminf(m3, d2);
    }

    // tail: clamp, sqrt, r = md/4 + 1e-6, w = 2^(0.35*log2 r) — HW transcendentals
    float o0, o1, o2, o3;
    {
        float md = hw_sqrt(fmaxf(m0, 0.0f));
        float r  = fmaf(md, 0.25f, 1e-6f);
        o0 = 1.0f - hw_exp2(0.35f * hw_log2(r));
    }
    {
        float md = hw_sqrt(fmaxf(m1, 0.0f));
        float r  = fmaf(md, 0.25f, 1e-6f);
        o1 = 1.0f - hw_exp2(0.35f * hw_log2(r));
    }
    {
        float md = hw_sqrt(fmaxf(m2, 0.0f));
        float r  = fmaf(md, 0.25f, 1e-6f);
        o2 = 1.0f - hw_exp2(0.35f * hw_log2(r));
    }
    {
        float md = hw_sqrt(fmaxf(m3, 0.0f));
        float r  = fmaf(md, 0.25f, 1e-6f);
        o3 = 1.0f - hw_exp2(0.35f * hw_log2(r));
    }

    const int idx = (b * HH + row) * WW + (lane << 2);
    *reinterpret_cast<float4*>(out + idx) = make_float4(o0, o1, o2, o3);
}

extern "C" void kernel_launch(void* const* d_in, const int* in_sizes, int n_in,
                              void* d_out, int out_size, void* d_ws, size_t ws_size,
                              hipStream_t stream) {
    const float* in = (const float*)d_in[0];
    float* out = (float*)d_out;
    // 32 images x 64 row-groups; 256 threads = 4 waves = 4 rows, 4 px/thread
    curve_render_kernel<<<dim3(NB * 64), dim3(256), 0, stream>>>(in, out);
}

// Round 10
// 13.165 us; speedup vs baseline: 1.9954x; 1.2332x over previous
//
#include <hip/hip_runtime.h>
#include <math.h>

// Numerics FROZEN (passed rounds 6/7/9): jax XLA:CPU f32 model —
//   f32 linspace t=RN(i*RN(1/31)); correctly-rounded powers (f64-emulated);
//   samples dot = sequential mul-then-add (no fma); cross: c0=RN(y*sy),
//   c=RN(fma(x,sx,c0)); e=RN(p2-2c) (2c exact -> fma(-2,c,p2) identical);
//   d2=RN(e+s2); min (exact, order-free); clamp; sqrt; r=fma(md,.25,1e-6);
//   w=2^(0.35*log2 r) via HW transcendentals (error << threshold margin).
// Round 10 (pure perf): packed FP32 (VOP3P v_pk_*, 2 f32/instr, bit-identical
// IEEE per half) + 8 px/thread. Per-sample scalars broadcast to SGPR PAIRS
// on the scalar pipe (free) and used as the single SGPR operand of each pk op.
#define OPAQ(x) asm volatile("" : "+v"(x))
typedef float f2 __attribute__((ext_vector_type(2)));

#define HH 256
#define WW 256
#define NS 32
#define NB 32

__device__ __forceinline__ uint64_t rlane_dup(float v, int lane) {
    unsigned u = (unsigned)__builtin_amdgcn_readlane(__builtin_bit_cast(int, v), lane);
    return ((uint64_t)u << 32) | (uint64_t)u;   // SALU pack: same f32 in both halves
}
__device__ __forceinline__ f2 pk_mul_vs(f2 a, uint64_t b) {
    f2 d; asm("v_pk_mul_f32 %0, %1, %2" : "=v"(d) : "v"(a), "s"(b)); return d;
}
__device__ __forceinline__ f2 pk_fma_vsv(f2 a, uint64_t b, f2 c) {
    f2 d; asm("v_pk_fma_f32 %0, %1, %2, %3" : "=v"(d) : "v"(a), "s"(b), "v"(c)); return d;
}
__device__ __forceinline__ f2 pk_fma_vvv(f2 a, f2 b, f2 c) {
    f2 d; asm("v_pk_fma_f32 %0, %1, %2, %3" : "=v"(d) : "v"(a), "v"(b), "v"(c)); return d;
}
__device__ __forceinline__ f2 pk_add_vs(f2 a, uint64_t b) {
    f2 d; asm("v_pk_add_f32 %0, %1, %2" : "=v"(d) : "v"(a), "s"(b)); return d;
}
__device__ __forceinline__ float hw_sqrt(float x) {
    float r; asm("v_sqrt_f32 %0, %1" : "=v"(r) : "v"(x)); return r;
}
__device__ __forceinline__ float hw_log2(float x) {
    float r; asm("v_log_f32 %0, %1" : "=v"(r) : "v"(x)); return r;
}
__device__ __forceinline__ float hw_exp2(float x) {
    float r; asm("v_exp_f32 %0, %1" : "=v"(r) : "v"(x)); return r;
}

// ---- frozen numeric core: sample s of one curve (EXACT round-6 ops) ----
__device__ __forceinline__ void curve_sample(const float* kp, int s,
                                             float& accy_o, float& accx_o, float& s2_o) {
    const float STEP = 1.0f / 31.0f;       // RN(1/31)
    float t = (float)s * STEP; OPAQ(t);    // f32 linspace (i=31 -> 1.0 after RN)
    float u = 1.0f - t;        OPAQ(u);
    // correctly-rounded powers (glibc powf) emulated via exact f64 products
    float t2 = (float)((double)t * (double)t);
    float t3 = (float)((double)t * (double)t * (double)t);
    float u2 = (float)((double)u * (double)u);
    float u3 = (float)((double)u * (double)u * (double)u);
    float b0 = u3;
    float m1 = 3.0f * t;  OPAQ(m1); float b1 = m1 * u2; OPAQ(b1);
    float m2 = 3.0f * t2; OPAQ(m2); float b2 = m2 * u;  OPAQ(b2);
    float b3 = t3;

    float ky0 = kp[0] * 256.0f, kx0 = kp[1] * 256.0f;   // exact (x 2^8)
    float ky1 = kp[2] * 256.0f, kx1 = kp[3] * 256.0f;
    float ky2 = kp[4] * 256.0f, kx2 = kp[5] * 256.0f;
    float ky3 = kp[6] * 256.0f, kx3 = kp[7] * 256.0f;

    // samples dot: sequential mul THEN add, no fma (XLA naive small-dot)
    float p, accy, accx;
    p = b0 * ky0; OPAQ(p); accy = p;
    p = b1 * ky1; OPAQ(p); accy = accy + p; OPAQ(accy);
    p = b2 * ky2; OPAQ(p); accy = accy + p; OPAQ(accy);
    p = b3 * ky3; OPAQ(p); accy = accy + p; OPAQ(accy);

    p = b0 * kx0; OPAQ(p); accx = p;
    p = b1 * kx1; OPAQ(p); accx = accx + p; OPAQ(accx);
    p = b2 * kx2; OPAQ(p); accx = accx + p; OPAQ(accx);
    p = b3 * kx3; OPAQ(p); accx = accx + p; OPAQ(accx);

    float q1 = accy * accy; OPAQ(q1);
    float q2 = accx * accx; OPAQ(q2);
    accy_o = accy; accx_o = accx; s2_o = q1 + q2;
}

__global__ __launch_bounds__(256) void curve_render_kernel(
    const float* __restrict__ in, float* __restrict__ out)
{
    const int b    = blockIdx.x >> 5;          // image
    const int rg   = blockIdx.x & 31;          // 8-row group
    const int wid  = threadIdx.x >> 6;         // wave: 2 rows
    const int lane = threadIdx.x & 63;
    const int row  = (rg << 3) + (wid << 1) + (lane >> 5);
    const int xb   = (lane & 31) << 3;         // 8 px per thread along x

    // every lane computes sample (lane & 31); lanes 32-63 duplicate 0-31
    float v_sy, v_sx, v_s2;
    curve_sample(in + b * 8, lane & 31, v_sy, v_sx, v_s2);

    const float y = (float)row;
    f2 yp = {y, y};
    const f2 M2 = {-2.0f, -2.0f};

    f2 xp0 = {(float)xb,       (float)(xb + 1)};
    f2 xp1 = {(float)(xb + 2), (float)(xb + 3)};
    f2 xp2 = {(float)(xb + 4), (float)(xb + 5)};
    f2 xp3 = {(float)(xb + 6), (float)(xb + 7)};
    const float yy = y * y;                    // exact
    f2 q0 = {yy + xp0.x * xp0.x, yy + xp0.y * xp0.y};   // p2, exact ints
    f2 q1 = {yy + xp1.x * xp1.x, yy + xp1.y * xp1.y};
    f2 q2 = {yy + xp2.x * xp2.x, yy + xp2.y * xp2.y};
    f2 q3 = {yy + xp3.x * xp3.x, yy + xp3.y * xp3.y};

    const float INF = 3.4028234663852886e38f;
    float m0 = INF, m1 = INF, m2 = INF, m3 = INF;
    float m4 = INF, m5 = INF, m6 = INF, m7 = INF;

    #pragma unroll
    for (int s = 0; s < NS; ++s) {
        const uint64_t syy = rlane_dup(v_sy, s);   // SGPR pair (SALU pack)
        const uint64_t sxx = rlane_dup(v_sx, s);
        const uint64_t s22 = rlane_dup(v_s2, s);
        // c0 = RN(y*sy), duplicated in both halves via (y,y)
        f2 c0 = pk_mul_vs(yp, syy);
        f2 c, e, d;
        c = pk_fma_vsv(xp0, sxx, c0); e = pk_fma_vvv(c, M2, q0); d = pk_add_vs(e, s22);
        m0 = fminf(m0, d.x); m1 = fminf(m1, d.y);
        c = pk_fma_vsv(xp1, sxx, c0); e = pk_fma_vvv(c, M2, q1); d = pk_add_vs(e, s22);
        m2 = fminf(m2, d.x); m3 = fminf(m3, d.y);
        c = pk_fma_vsv(xp2, sxx, c0); e = pk_fma_vvv(c, M2, q2); d = pk_add_vs(e, s22);
        m4 = fminf(m4, d.x); m5 = fminf(m5, d.y);
        c = pk_fma_vsv(xp3, sxx, c0); e = pk_fma_vvv(c, M2, q3); d = pk_add_vs(e, s22);
        m6 = fminf(m6, d.x); m7 = fminf(m7, d.y);
    }

    // tail: clamp, HW sqrt, r = fma(md,0.25,1e-6), w = 2^(0.35*log2 r)
    float o0, o1, o2, o3, o4, o5, o6, o7;
    #define TAIL(mi, oi) { \
        float md = hw_sqrt(fmaxf(mi, 0.0f)); \
        float r  = fmaf(md, 0.25f, 1e-6f); \
        oi = 1.0f - hw_exp2(0.35f * hw_log2(r)); }
    TAIL(m0, o0) TAIL(m1, o1) TAIL(m2, o2) TAIL(m3, o3)
    TAIL(m4, o4) TAIL(m5, o5) TAIL(m6, o6) TAIL(m7, o7)
    #undef TAIL

    const int idx = (b * HH + row) * WW + xb;
    *reinterpret_cast<float4*>(out + idx)     = make_float4(o0, o1, o2, o3);
    *reinterpret_cast<float4*>(out + idx + 4) = make_float4(o4, o5, o6, o7);
}

extern "C" void kernel_launch(void* const* d_in, const int* in_sizes, int n_in,
                              void* d_out, int out_size, void* d_ws, size_t ws_size,
                              hipStream_t stream) {
    const float* in = (const float*)d_in[0];
    float* out = (float*)d_out;
    // 32 images x 32 groups of 8 rows; 256 threads = 4 waves = 8 rows, 8 px/thread
    curve_render_kernel<<<dim3(NB * 32), dim3(256), 0, stream>>>(in, out);
}